// Round 3
// baseline (77.932 us; speedup 1.0000x reference)
//
#include <hip/hip_runtime.h>
#include <hip/hip_bf16.h>
#include <stdint.h>

#define NROWS 8192
#define BROWS 4096
#define D 256
#define SQRT_SCALE 3.7982826f   // sqrt((1/T)*log2(e)), T=0.1
#define LN2 0.6931471805599453f
#define TILE 128
#define NBLK 2080               // 64*65/2 upper-tri 128x128 tiles

typedef __attribute__((ext_vector_type(8))) short bf16x8;
typedef __attribute__((ext_vector_type(4))) float f32x4;

template<int M> struct IC { static constexpr int v = M; };

__device__ inline void gload_lds16(const void* g, void* l) {
  __builtin_amdgcn_global_load_lds((const __attribute__((address_space(1))) void*)g,
                                   (__attribute__((address_space(3))) void*)l,
                                   16, 0, 0);
}

__device__ inline unsigned short f2bf(float x) {
  __hip_bfloat16 h = __float2bfloat16(x);
  return __builtin_bit_cast(unsigned short, h);
}

// Kernel A: L2-normalize rows, scale by sqrt((1/T)log2e), -> bf16 reps; zero denom/out.
__global__ __launch_bounds__(256) void knorm(const float* __restrict__ zi,
                                             const float* __restrict__ zj,
                                             unsigned short* __restrict__ reps,
                                             float* __restrict__ denom,
                                             float* __restrict__ out) {
  int w = threadIdx.x >> 6, l = threadIdx.x & 63;
  int row = blockIdx.x * 4 + w;
  const float* src = (row < BROWS) ? (zi + (size_t)row * D)
                                   : (zj + (size_t)(row - BROWS) * D);
  float4 v = ((const float4*)src)[l];
  float ss = v.x * v.x + v.y * v.y + v.z * v.z + v.w * v.w;
#pragma unroll
  for (int m = 1; m < 64; m <<= 1) ss += __shfl_xor(ss, m, 64);
  float sc = SQRT_SCALE / fmaxf(sqrtf(ss), 1e-12f);
  ushort4 o;
  o.x = f2bf(v.x * sc); o.y = f2bf(v.y * sc);
  o.z = f2bf(v.z * sc); o.w = f2bf(v.w * sc);
  ((ushort4*)reps)[(size_t)row * 64 + l] = o;
  if (l == 0) denom[row] = 0.f;
  if (row == 0 && l == 0) out[0] = 0.f;
}

// Kernel B: one 128x128 upper-tri tile per block. sim scaled so e = exp2(acc).
// Off-diag tiles feed denom[row] AND denom[col]; diag tiles mask rg==cg;
// tiles with jt-it==32 capture pos[rg] = acc (the scaled positive similarity).
__global__ __launch_bounds__(256, 2) void ksim(const unsigned short* __restrict__ reps_,
                                               float* __restrict__ denom,
                                               float* __restrict__ pos) {
  __shared__ uint4 smem[4096];  // 128 rows x 512 B = 64 KB
  const uint4* reps4 = (const uint4*)reps_;
  int tid = threadIdx.x, w = tid >> 6, l = tid & 63;
  int wr = w >> 1, wc = w & 1;       // wave quadrant: 64 rows x 64 cols
  int kgrp = l >> 4;

  // ---- triangular tile index: b -> (it, jt), it <= jt, off(i)=i*(129-i)/2 ----
  int b = blockIdx.x;
  int it = (int)(64.5f - sqrtf(4160.25f - 2.0f * (float)b));
  if (it < 0) it = 0;
  if (it > 63) it = 63;
  while (it < 63 && (it + 1) * (129 - (it + 1)) / 2 <= b) ++it;
  while (it > 0 && it * (129 - it) / 2 > b) --it;
  int jt = it + (b - it * (129 - it) / 2);
  int rb = it * TILE, cb = jt * TILE;

  // ---- stage B tile (reps rows cb..cb+127) to LDS; linear dest, swizzled src ----
#pragma unroll
  for (int i = 0; i < 16; ++i) {
    int c = w + 4 * i;               // 64 chunks of 1 KB (2 rows each)
    int lr = 2 * c + (l >> 5);
    int kb = ((l & 31) * 16) ^ ((lr & 7) << 4);
    gload_lds16((const char*)reps_ + (size_t)(cb + lr) * 512 + kb,
                (void*)&smem[c * 64]);
  }

  // ---- A fragments in registers: lane holds row rb+wr*64+fr*16+(l&15),
  //      k = kk*32 + kgrp*8 .. +8 ----
  bf16x8 a[4][8];
  int arow = rb + wr * 64 + (l & 15);
#pragma unroll
  for (int fr = 0; fr < 4; ++fr) {
    const uint4* base = reps4 + (size_t)(arow + fr * 16) * 32 + kgrp;
#pragma unroll
    for (int kk = 0; kk < 8; ++kk)
      a[fr][kk] = __builtin_bit_cast(bf16x8, base[kk * 4]);
  }

  f32x4 acc[4][4];
#pragma unroll
  for (int fr = 0; fr < 4; ++fr)
#pragma unroll
    for (int fc = 0; fc < 4; ++fc)
#pragma unroll
      for (int r = 0; r < 4; ++r) acc[fr][fc][r] = 0.f;

  __syncthreads();

  // ---- MFMA: K=256 in 8 steps; 16 MFMA + 4 ds_read_b128 per step per wave ----
#pragma unroll
  for (int kk = 0; kk < 8; ++kk) {
    int kb = kk * 64 + kgrp * 16;
    bf16x8 bf[4];
#pragma unroll
    for (int fc = 0; fc < 4; ++fc) {
      int lr = wc * 64 + fc * 16 + (l & 15);
      bf[fc] = *(const bf16x8*)&smem[lr * 32 + ((kb ^ ((lr & 7) << 4)) >> 4)];
    }
#pragma unroll
    for (int fr = 0; fr < 4; ++fr)
#pragma unroll
      for (int fc = 0; fc < 4; ++fc)
        acc[fr][fc] = __builtin_amdgcn_mfma_f32_16x16x32_bf16(a[fr][kk], bf[fc],
                                                              acc[fr][fc], 0, 0, 0);
  }

  // ---- epilogue: e = exp2(acc); rowsum always, colsum for off-diag ----
  float rowsum[4][4];
#pragma unroll
  for (int fr = 0; fr < 4; ++fr)
#pragma unroll
    for (int r = 0; r < 4; ++r) rowsum[fr][r] = 0.f;
  float cs0 = 0.f, cs1 = 0.f, cs2 = 0.f, cs3 = 0.f;
  int r0 = rb + wr * 64 + kgrp * 4;   // + fr*16 + r
  int c0 = cb + wc * 64 + (l & 15);   // + fc*16

  auto epi = [&](auto mode) {
    constexpr int MODE = decltype(mode)::v;  // 0 plain, 1 diag, 2 pos
#pragma unroll
    for (int fr = 0; fr < 4; ++fr)
#pragma unroll
      for (int fc = 0; fc < 4; ++fc)
#pragma unroll
        for (int r = 0; r < 4; ++r) {
          int rg = r0 + fr * 16 + r;
          int cg = c0 + fc * 16;
          float s = acc[fr][fc][r];
          float e = __builtin_amdgcn_exp2f(s);
          if (MODE == 1) e = (rg == cg) ? 0.f : e;
          if (MODE == 2) { if (cg == rg + BROWS) pos[rg] = s; }
          rowsum[fr][r] += e;
          if (MODE != 1) {
            if (fc == 0) cs0 += e; else if (fc == 1) cs1 += e;
            else if (fc == 2) cs2 += e; else cs3 += e;
          }
        }
  };
  if (it == jt)           epi(IC<1>{});
  else if (jt == it + 32) epi(IC<2>{});
  else                    epi(IC<0>{});

  // ---- row sums: reduce across 16 lanes sharing each row; 4-lane atomics ----
#pragma unroll
  for (int fr = 0; fr < 4; ++fr)
#pragma unroll
    for (int r = 0; r < 4; ++r) {
      float v = rowsum[fr][r];
      v += __shfl_xor(v, 1, 64);
      v += __shfl_xor(v, 2, 64);
      v += __shfl_xor(v, 4, 64);
      v += __shfl_xor(v, 8, 64);
      if ((l & 15) == 0) atomicAdd(&denom[r0 + fr * 16 + r], v);
    }

  // ---- col sums (off-diag): reduce across the 4 row-groups; 64-lane atomic ----
  if (it != jt) {
    cs0 += __shfl_xor(cs0, 16, 64); cs0 += __shfl_xor(cs0, 32, 64);
    cs1 += __shfl_xor(cs1, 16, 64); cs1 += __shfl_xor(cs1, 32, 64);
    cs2 += __shfl_xor(cs2, 16, 64); cs2 += __shfl_xor(cs2, 32, 64);
    cs3 += __shfl_xor(cs3, 16, 64); cs3 += __shfl_xor(cs3, 32, 64);
    float v = (kgrp == 0) ? cs0 : (kgrp == 1) ? cs1 : (kgrp == 2) ? cs2 : cs3;
    atomicAdd(&denom[cb + wc * 64 + kgrp * 16 + (l & 15)], v);
  }
}

// Kernel F: + (1/N) * sum_i (log(denom_i) - posS_{i mod B} * ln2)
__global__ __launch_bounds__(256) void kfin(const float* __restrict__ denom,
                                            const float* __restrict__ pos,
                                            float* __restrict__ out) {
  int i = blockIdx.x * 256 + threadIdx.x;
  float v = (logf(denom[i]) - pos[i & 4095] * LN2) * (1.0f / 8192.0f);
#pragma unroll
  for (int m = 1; m < 64; m <<= 1) v += __shfl_xor(v, m, 64);
  __shared__ float part[4];
  if ((threadIdx.x & 63) == 0) part[threadIdx.x >> 6] = v;
  __syncthreads();
  if (threadIdx.x == 0)
    atomicAdd(out, part[0] + part[1] + part[2] + part[3]);
}

extern "C" void kernel_launch(void* const* d_in, const int* in_sizes, int n_in,
                              void* d_out, int out_size, void* d_ws, size_t ws_size,
                              hipStream_t stream) {
  (void)in_sizes; (void)n_in; (void)out_size; (void)ws_size;
  const float* zi = (const float*)d_in[0];
  const float* zj = (const float*)d_in[1];
  float* out = (float*)d_out;
  char* ws = (char*)d_ws;
  unsigned short* reps = (unsigned short*)ws;                 // 4 MB
  float* denom = (float*)(ws + 4194304);                      // 32 KB
  float* pos   = (float*)(ws + 4194304 + 32768);              // 16 KB

  knorm<<<2048, 256, 0, stream>>>(zi, zj, reps, denom, out);
  ksim<<<NBLK, 256, 0, stream>>>(reps, denom, pos);
  kfin<<<32, 256, 0, stream>>>(denom, pos, out);
}

// Round 4
// 47.177 us; speedup vs baseline: 1.6519x; 1.6519x over previous
//
#include <hip/hip_runtime.h>
#include <hip/hip_bf16.h>
#include <stdint.h>

#define NROWS 8192
#define BROWS 4096
#define D 256
#define SQRT_SCALE 3.7982826f   // sqrt((1/T)*log2(e)), T=0.1
#define LN2 0.6931471805599453f
#define NBLK 544                // sum_{it=0}^{63} (16 - it/4)

typedef __attribute__((ext_vector_type(8))) short bf16x8;
typedef __attribute__((ext_vector_type(4))) float f32x4;

__device__ inline void gload_lds16(const void* g, void* l) {
  __builtin_amdgcn_global_load_lds((const __attribute__((address_space(1))) void*)g,
                                   (__attribute__((address_space(3))) void*)l,
                                   16, 0, 0);
}

__device__ inline unsigned short f2bf(float x) {
  __hip_bfloat16 h = __float2bfloat16(x);
  return __builtin_bit_cast(unsigned short, h);
}

// Kernel A: L2-normalize rows, scale by sqrt((1/T)log2e), -> bf16 reps; zero denom/out.
__global__ __launch_bounds__(256) void knorm(const float* __restrict__ zi,
                                             const float* __restrict__ zj,
                                             unsigned short* __restrict__ reps,
                                             float* __restrict__ denom,
                                             float* __restrict__ out) {
  int w = threadIdx.x >> 6, l = threadIdx.x & 63;
  int row = blockIdx.x * 4 + w;
  const float* src = (row < BROWS) ? (zi + (size_t)row * D)
                                   : (zj + (size_t)(row - BROWS) * D);
  float4 v = ((const float4*)src)[l];
  float ss = v.x * v.x + v.y * v.y + v.z * v.z + v.w * v.w;
#pragma unroll
  for (int m = 1; m < 64; m <<= 1) ss += __shfl_xor(ss, m, 64);
  float sc = SQRT_SCALE / fmaxf(sqrtf(ss), 1e-12f);
  ushort4 o;
  o.x = f2bf(v.x * sc); o.y = f2bf(v.y * sc);
  o.z = f2bf(v.z * sc); o.w = f2bf(v.w * sc);
  ((ushort4*)reps)[(size_t)row * 64 + l] = o;
  if (l == 0) denom[row] = 0.f;
  if (row == 0 && l == 0) out[0] = 0.f;
}

// Kernel B: strip-streaming upper-tri sim. Block = (128-row strip it, 512-col chunk q).
// A in registers; 32-col B tiles double-buffered in LDS; e=exp2(acc) fed to
// rowsum (regs) and colsum (per-wave LDS, skipped for the diag 128-col window).
__global__ __launch_bounds__(256, 3) void ksim(const unsigned short* __restrict__ reps_,
                                               float* __restrict__ denom,
                                               float* __restrict__ pos) {
  __shared__ uint4 smem[2][1024];     // 2 x 32 rows x 512 B = 32 KB
  __shared__ float colacc[4][512];    // per-wave column accumulators, 8 KB
  const uint4* reps4 = (const uint4*)reps_;
  int tid = threadIdx.x, w = tid >> 6, l = tid & 63;
  int kgrp = l >> 4;

  // ---- block -> (strip it, chunk q); chunks(it) = 16 - it/4, total 544 ----
  int rem = blockIdx.x, it = 0;
  while (rem >= 16 - (it >> 2)) { rem -= 16 - (it >> 2); ++it; }
  int q = rem;
  int rowbase = it * 128;
  int cs0 = rowbase + q * 512;                 // chunk col start
  int niter = (NROWS - cs0) / 32; if (niter > 16) niter = 16;

  // ---- zero colacc ----
  float* ca = &colacc[0][0];
#pragma unroll
  for (int i = 0; i < 8; ++i) ca[tid + 256 * i] = 0.f;

  // ---- A fragments: wave w owns rows rowbase+32w..+32; lane holds
  //      row +fr*16+(l&15), k bytes [kk*64 + kgrp*16, +16) ----
  bf16x8 a[2][8];
  int arow = rowbase + w * 32 + (l & 15);
#pragma unroll
  for (int fr = 0; fr < 2; ++fr) {
    const uint4* base = reps4 + (size_t)(arow + fr * 16) * 32 + kgrp;
#pragma unroll
    for (int kk = 0; kk < 8; ++kk)
      a[fr][kk] = __builtin_bit_cast(bf16x8, base[kk * 4]);
  }

  // ---- staging: 32 reps-rows x 512B -> 16KB buffer; linear dest, swizzled src ----
  auto stage = [&](int bufi, int colbase) {
#pragma unroll
    for (int i = 0; i < 4; ++i) {
      int ch = w * 4 + i;              // 16 chunks of 1 KB (2 rows each)
      int lr = 2 * ch + (l >> 5);
      int kb = ((l & 31) * 16) ^ ((lr & 7) << 4);
      gload_lds16((const char*)reps_ + (size_t)(colbase + lr) * 512 + kb,
                  (void*)&smem[bufi][ch * 64]);
    }
  };

  float rowsum[2][4];
#pragma unroll
  for (int fr = 0; fr < 2; ++fr)
#pragma unroll
    for (int r = 0; r < 4; ++r) rowsum[fr][r] = 0.f;

  stage(0, cs0);
  __syncthreads();
  int buf = 0;
  bool posChunk = (q == 8) && (it < 32);
  int r0 = rowbase + w * 32 + kgrp * 4;

  for (int t = 0; t < niter; ++t) {
    if (t + 1 < niter) stage(buf ^ 1, cs0 + 32 * (t + 1));
    int cb = cs0 + 32 * t;

    // ---- MFMA: K=256, 8 steps; 2 ds_read_b128 + 4 MFMA per step per wave ----
    f32x4 acc[2][2];
    const f32x4 zero = {0.f, 0.f, 0.f, 0.f};
#pragma unroll
    for (int kk = 0; kk < 8; ++kk) {
      int kb = kk * 64 + kgrp * 16;
      bf16x8 b0, b1;
      {
        int lr = (l & 15);
        b0 = *(const bf16x8*)&smem[buf][lr * 32 + ((kb ^ ((lr & 7) << 4)) >> 4)];
        int lr1 = 16 + (l & 15);
        b1 = *(const bf16x8*)&smem[buf][lr1 * 32 + ((kb ^ ((lr1 & 7) << 4)) >> 4)];
      }
#pragma unroll
      for (int fr = 0; fr < 2; ++fr) {
        if (kk == 0) {
          acc[fr][0] = __builtin_amdgcn_mfma_f32_16x16x32_bf16(a[fr][0], b0, zero, 0, 0, 0);
          acc[fr][1] = __builtin_amdgcn_mfma_f32_16x16x32_bf16(a[fr][0], b1, zero, 0, 0, 0);
        } else {
          acc[fr][0] = __builtin_amdgcn_mfma_f32_16x16x32_bf16(a[fr][kk], b0, acc[fr][0], 0, 0, 0);
          acc[fr][1] = __builtin_amdgcn_mfma_f32_16x16x32_bf16(a[fr][kk], b1, acc[fr][1], 0, 0, 0);
        }
      }
    }

    // ---- epilogue: e=exp2(acc), diag mask, rowsum + col partials ----
    bool docol = !(q == 0 && t < 4);          // diag 128-col window: rowsum only
    bool dopos = posChunk && (t < 4);
    float cp0 = 0.f, cp1 = 0.f;
    int cbase = cb + (l & 15);
#pragma unroll
    for (int fr = 0; fr < 2; ++fr)
#pragma unroll
      for (int fc = 0; fc < 2; ++fc)
#pragma unroll
        for (int r = 0; r < 4; ++r) {
          int rg = r0 + fr * 16 + r;
          int cg = cbase + fc * 16;
          float s = acc[fr][fc][r];
          float e = __builtin_amdgcn_exp2f(s);
          e = (rg == cg) ? 0.f : e;
          if (dopos && cg == rg + BROWS) pos[rg] = s;
          rowsum[fr][r] += e;
          if (fc == 0) cp0 += e; else cp1 += e;
        }
    if (docol) {
      cp0 += __shfl_xor(cp0, 16, 64); cp0 += __shfl_xor(cp0, 32, 64);
      cp1 += __shfl_xor(cp1, 16, 64); cp1 += __shfl_xor(cp1, 32, 64);
      if (l < 16) {
        int off = (cb - cs0) + l;
        colacc[w][off] += cp0;
        colacc[w][off + 16] += cp1;
      }
    }
    __syncthreads();
    buf ^= 1;
  }

  // ---- row sums: reduce 16 col-lanes; 4 lanes atomic per wave ----
#pragma unroll
  for (int fr = 0; fr < 2; ++fr)
#pragma unroll
    for (int r = 0; r < 4; ++r) {
      float v = rowsum[fr][r];
      v += __shfl_xor(v, 1, 64);
      v += __shfl_xor(v, 2, 64);
      v += __shfl_xor(v, 4, 64);
      v += __shfl_xor(v, 8, 64);
      if ((l & 15) == 0) atomicAdd(&denom[r0 + fr * 16 + r], v);
    }

  // ---- col sums: combine 4 wave regions, one atomic per column ----
  __syncthreads();
#pragma unroll
  for (int i = 0; i < 2; ++i) {
    int off = tid + 256 * i;
    float v = colacc[0][off] + colacc[1][off] + colacc[2][off] + colacc[3][off];
    int col = cs0 + off;
    if (col < NROWS && v != 0.f) atomicAdd(&denom[col], v);
  }
}

// Kernel F: + (1/N) * sum_i (log(denom_i) - posS_{i mod B} * ln2)
__global__ __launch_bounds__(256) void kfin(const float* __restrict__ denom,
                                            const float* __restrict__ pos,
                                            float* __restrict__ out) {
  int i = blockIdx.x * 256 + threadIdx.x;
  float v = (logf(denom[i]) - pos[i & 4095] * LN2) * (1.0f / 8192.0f);
#pragma unroll
  for (int m = 1; m < 64; m <<= 1) v += __shfl_xor(v, m, 64);
  __shared__ float part[4];
  if ((threadIdx.x & 63) == 0) part[threadIdx.x >> 6] = v;
  __syncthreads();
  if (threadIdx.x == 0)
    atomicAdd(out, part[0] + part[1] + part[2] + part[3]);
}

extern "C" void kernel_launch(void* const* d_in, const int* in_sizes, int n_in,
                              void* d_out, int out_size, void* d_ws, size_t ws_size,
                              hipStream_t stream) {
  (void)in_sizes; (void)n_in; (void)out_size; (void)ws_size;
  const float* zi = (const float*)d_in[0];
  const float* zj = (const float*)d_in[1];
  float* out = (float*)d_out;
  char* ws = (char*)d_ws;
  unsigned short* reps = (unsigned short*)ws;                 // 4 MB
  float* denom = (float*)(ws + 4194304);                      // 32 KB
  float* pos   = (float*)(ws + 4194304 + 32768);              // 16 KB

  knorm<<<2048, 256, 0, stream>>>(zi, zj, reps, denom, out);
  ksim<<<NBLK, 256, 0, stream>>>(reps, denom, pos);
  kfin<<<32, 256, 0, stream>>>(denom, pos, out);
}